// Round 7
// baseline (5645.275 us; speedup 1.0000x reference)
//
#include <hip/hip_runtime.h>

// ============================================================================
// BiLSTM + CRF Viterbi.  Round 7: recurrence critical-path surgery.
//  - xp register-prefetched one step ahead (issued AFTER h-frag loads so the
//    FIFO vmcnt never forces xp's HBM latency onto the poll/MFMA waits).
//  - Polls at loop top: wave0 polls dir0 || wave1 polls dir1, one syncthreads.
//  - fA+fB loaded together at top; mfmaB overlaps hA store-drain (before S2).
//  - h stores widened to u64 (atomic relaxed agent).
//  - Numerics identical to R6 (single bf16, absmax=18=1 tag flip, safe).
// ============================================================================

#define B_ 64
#define T_ 512
#define NT_ 24

typedef __attribute__((ext_vector_type(8))) short bf16x8;
typedef __attribute__((ext_vector_type(4))) float f32x4;
typedef __attribute__((ext_vector_type(4))) unsigned int u32x4;

#define MFMA16(a, b, c) __builtin_amdgcn_mfma_f32_16x16x32_bf16(a, b, c, 0, 0, 0)

__device__ __forceinline__ unsigned short f2bf(float x) {
  unsigned u = __float_as_uint(x);
  u += 0x7FFFu + ((u >> 16) & 1u);  // round-to-nearest-even
  return (unsigned short)(u >> 16);
}
__device__ __forceinline__ float bf2f(unsigned short h) {
  return __uint_as_float(((unsigned)h) << 16);
}

// ---------------- ws layout (bytes) ----------------
#define O_WHHB  ((size_t)0)                     // [dir][2048][512] u16 = 4MB
#define O_WIHB  ((size_t)4194304)               // [dir][2048][512] u16 = 4MB
#define O_XB    ((size_t)8388608)               // [64][512][512] u16 = 32MB
#define O_OUT   ((size_t)41943040)              // [dir][b][t][512] u16 = 64MB
#define SZ_OUT  ((size_t)67108864)
#define O_HX    ((size_t)109051904)             // [dir][buf][64][256] u32 = 256KB
#define SZ_HX   ((size_t)262144)
#define O_HF    ((size_t)109314048)             // [dir][64][512] f32
#define O_CF    ((size_t)109576192)
#define O_EMIS  ((size_t)109838336)             // [64][512][24] f32 = 3MB
#define O_BAR   ((size_t)112984064)             // 512B arrival arrays
#define O_XP    ((size_t)112984576)             // [2][Tc][64][2048] f32 = Tc MiB

// ---------------- fp32 -> bf16 cast ----------------
__global__ void cast_bf(const float* __restrict__ src,
                        unsigned short* __restrict__ dst, int n) {
  int i = (blockIdx.x * blockDim.x + threadIdx.x) * 4;
  int stride = gridDim.x * blockDim.x * 4;
  for (; i < n; i += stride) {
    float4 v = *(const float4*)(src + i);
    ushort4 o;
    o.x = f2bf(v.x); o.y = f2bf(v.y); o.z = f2bf(v.z); o.w = f2bf(v.w);
    *(ushort4*)(dst + i) = o;
  }
}

// ---------------- xp GEMM (unchanged from R6) ----------------
__global__ __launch_bounds__(256) void xp_gemm(
    const unsigned short* __restrict__ xb,      // [64][512][512] bf16
    const unsigned short* __restrict__ wih,     // [dir][2048][512] bf16
    const float* __restrict__ bias_f, const float* __restrict__ bias_b,
    const int* __restrict__ length,
    float* __restrict__ xp, int t0, int Tc) {
  __shared__ char smem[32768];   // A[128][64] | B[128][64] bf16
  __shared__ int rowoff[128];
  const int tid = threadIdx.x;
  const int dir = blockIdx.z;
  const int m0 = blockIdx.x * 128;
  const int n0 = blockIdx.y * 128;
  if (tid < 128) {
    int m = m0 + tid;
    int tt = t0 + (m >> 6);
    int b = m & 63;
    int st = tt;
    if (dir) { st = length[b] - 1 - tt; st = st < 0 ? 0 : (st > 511 ? 511 : st); }
    rowoff[tid] = (b * 512 + st) * 512;
  }
  __syncthreads();
  const unsigned short* wih_d = wih + (size_t)dir * 1048576;
  f32x4 acc[4][4];
#pragma unroll
  for (int i = 0; i < 4; ++i)
#pragma unroll
    for (int j = 0; j < 4; ++j) acc[i][j] = f32x4{0.f, 0.f, 0.f, 0.f};
  const int w = tid >> 6, l = tid & 63;
  const int wm = w & 1, wn = w >> 1;
  for (int ks = 0; ks < 8; ++ks) {
    int k0 = ks * 64;
    __syncthreads();
#pragma unroll
    for (int r = 0; r < 8; ++r) {
      int u = tid + 256 * r;
      int plane = u >> 10;
      int rem = u & 1023;
      int row = rem >> 3, cph = rem & 7;
      int koff = k0 + (cph ^ (row & 7)) * 8;
      const unsigned short* src;
      if (plane == 0) src = xb + rowoff[row] + koff;
      else src = wih_d + (n0 + row) * 512 + koff;
      *(uint4*)(smem + u * 16) = *(const uint4*)src;
    }
    __syncthreads();
#pragma unroll
    for (int kf = 0; kf < 2; ++kf) {
      bf16x8 ah[4], bh[4];
#pragma unroll
      for (int x = 0; x < 4; ++x) {
        int arow = wm * 64 + x * 16 + (l & 15);
        int ac = (kf * 4 + (l >> 4)) ^ (arow & 7);
        ah[x] = *(const bf16x8*)(smem + arow * 128 + ac * 16);
        int brow = wn * 64 + x * 16 + (l & 15);
        int bc = (kf * 4 + (l >> 4)) ^ (brow & 7);
        bh[x] = *(const bf16x8*)(smem + 16384 + brow * 128 + bc * 16);
      }
#pragma unroll
      for (int mi = 0; mi < 4; ++mi)
#pragma unroll
        for (int ni = 0; ni < 4; ++ni)
          acc[mi][ni] = MFMA16(ah[mi], bh[ni], acc[mi][ni]);
    }
  }
  const float* bias = dir ? bias_b : bias_f;
  float* xpd = xp + (size_t)dir * (size_t)Tc * 131072;
#pragma unroll
  for (int mi = 0; mi < 4; ++mi)
#pragma unroll
    for (int ni = 0; ni < 4; ++ni)
#pragma unroll
      for (int i = 0; i < 4; ++i) {
        int m = m0 + wm * 64 + mi * 16 + (l >> 4) * 4 + i;
        int nn = n0 + wn * 64 + ni * 16 + (l & 15);
        xpd[(size_t)m * 2048 + nn] = acc[mi][ni][i] + bias[nn];
      }
}

// ---------------- persistent recurrence v4 ----------------
__global__ __launch_bounds__(512) void lstm_persist(
    const unsigned short* __restrict__ whh,     // [dir][2048][512] bf16
    unsigned* hx,                               // [dir][buf][64][256] u32
    const float* __restrict__ xp,               // [dir][Tc][64][2048]
    const int* __restrict__ length,
    float* __restrict__ Cst, float* __restrict__ Hst,
    unsigned short* __restrict__ outbf,         // [dir][b][t][512] bf16
    unsigned* arrv, int t0, int Tc) {
  __shared__ char smem[100352];  // W[2dir][32r][1024B] | gex[2dir][2kh][64][34]f32
  const int tid = threadIdx.x;
  const int wg = blockIdx.x;     // 0..63
  const int j0 = wg * 8;
  // ---- stage W once (both dirs), 1024B rows + granule-XOR ----
  for (int u = tid; u < 4096; u += 512) {
    int dir = u >> 11, rem = u & 2047;
    int r = rem >> 6, cph = rem & 63;
    int klog = cph ^ (r & 7);
    int grow = (r >> 3) * 512 + j0 + (r & 7);
    const unsigned short* src = whh + (size_t)dir * 1048576 + grow * 512 + klog * 8;
    *(uint4*)(smem + dir * 32768 + r * 1024 + cph * 16) = *(const uint4*)src;
  }
  const int l = tid & 63;
  const int w = tid >> 6;
  const int mh = w >> 1, kh = w & 1;
  const int b = tid >> 3, jj = tid & 7;
  const int j = j0 + jj;
  const int lenb = length[b];
  const int rowA = 16 * mh + (l & 15);
  const int q = l >> 4;
  const int r0 = l & 15, r1 = 16 + (l & 15);
  float* gex = (float*)(smem + 65536);  // [dir][kh][64][34]
  float c0, h0, c1, h1;
  const size_t s0 = (size_t)b * 512 + j;
  const size_t s1 = (size_t)(64 + b) * 512 + j;
  if (t0 == 0) { c0 = h0 = c1 = h1 = 0.f; }
  else { c0 = Cst[s0]; h0 = Hst[s0]; c1 = Cst[s1]; h1 = Hst[s1]; }
  __syncthreads();  // W staged

  // xp: current step in regs, prefetched one step ahead inside the loop
  const float* xpb0 = xp + b * 2048 + j;
  const float* xpb1 = xpb0 + (size_t)Tc * 131072;
  float xA0 = xpb0[0], xA1 = xpb0[512], xA2 = xpb0[1024], xA3 = xpb0[1536];
  float xB0 = xpb1[0], xB1 = xpb1[512], xB2 = xpb1[1024], xB3 = xpb1[1536];

  for (int tl = 0; tl < Tc; ++tl) {
    const int t = t0 + tl;
    const int cur = t & 1;
    // ---- polls at top: wave0 = dir0, wave1 = dir1 (parallel) ----
    if (tl > 0 && w < 2) {
      const unsigned* grp = arrv + (w ? 64 : 0);
      const unsigned e = (unsigned)tl;
      while (true) {
        unsigned v = __hip_atomic_load(&grp[l], __ATOMIC_RELAXED,
                                       __HIP_MEMORY_SCOPE_AGENT);
        if (__all((int)(v >= e))) break;
        __builtin_amdgcn_s_sleep(1);
      }
    }
    __syncthreads();  // S0: both dirs confirmed ready
    asm volatile("" ::: "memory");
    // ---- load A frags for BOTH dirs (nt 16B, fragment layout) ----
    const char* hA = (const char*)hx + (size_t)cur * 65536;
    const char* hB = (const char*)hx + (size_t)(2 + cur) * 65536;
    u32x4 fA[8], fB[8];
#pragma unroll
    for (int kc = 0; kc < 8; ++kc) {
      fA[kc] = __builtin_nontemporal_load(
          (const u32x4*)(hA + rowA * 1024 + (kh * 8 + kc) * 64 + q * 16));
      fB[kc] = __builtin_nontemporal_load(
          (const u32x4*)(hB + rowA * 1024 + (kh * 8 + kc) * 64 + q * 16));
    }
    // ---- xp prefetch for NEXT step (younger than f-loads -> never blocks) --
    int tn = (tl + 1 < Tc) ? tl + 1 : tl;
    const float* xn0 = xpb0 + (size_t)tn * 131072;
    const float* xn1 = xpb1 + (size_t)tn * 131072;
    float nA0 = xn0[0], nA1 = xn0[512], nA2 = xn0[1024], nA3 = xn0[1536];
    float nB0 = xn1[0], nB1 = xn1[512], nB2 = xn1[1024], nB3 = xn1[1536];
    // ---- MFMA dir0 ----
    f32x4 aA0 = f32x4{0.f, 0.f, 0.f, 0.f}, aA1 = f32x4{0.f, 0.f, 0.f, 0.f};
#pragma unroll
    for (int kc = 0; kc < 8; ++kc) {
      bf16x8 av = __builtin_bit_cast(bf16x8, fA[kc]);
      int kg = (kh * 8 + kc) * 4 + q;
      bf16x8 b0v = *(const bf16x8*)(smem + r0 * 1024 + (kg ^ (r0 & 7)) * 16);
      bf16x8 b1v = *(const bf16x8*)(smem + r1 * 1024 + (kg ^ (r1 & 7)) * 16);
      aA0 = MFMA16(av, b0v, aA0);
      aA1 = MFMA16(av, b1v, aA1);
    }
    {
      float* gA = gex + kh * 2176;
#pragma unroll
      for (int i = 0; i < 4; ++i) {
        gA[(16 * mh + 4 * q + i) * 34 + r0] = aA0[i];
        gA[(16 * mh + 4 * q + i) * 34 + r1] = aA1[i];
      }
    }
    __syncthreads();  // S1: gexA ready
    const bool m = (t < lenb);
    // ---- gate dir0 + hA store (u64 packed) ----
    {
      float g0 = gex[b * 34 + jj]      + gex[2176 + b * 34 + jj]      + xA0;
      float g1 = gex[b * 34 + 8 + jj]  + gex[2176 + b * 34 + 8 + jj]  + xA1;
      float g2 = gex[b * 34 + 16 + jj] + gex[2176 + b * 34 + 16 + jj] + xA2;
      float g3 = gex[b * 34 + 24 + jj] + gex[2176 + b * 34 + 24 + jj] + xA3;
      float ig = 1.f / (1.f + expf(-g0));
      float fg = 1.f / (1.f + expf(-g1));
      float gg = tanhf(g2);
      float og = 1.f / (1.f + expf(-g3));
      float cn = fg * c0 + ig * gg;
      float hn = og * tanhf(cn);
      c0 = m ? cn : c0;
      h0 = m ? hn : h0;
      unsigned short hb = f2bf(h0);
      float hp1 = __shfl(h0, (l + 1) & 63);
      unsigned p32 = (unsigned)hb | ((unsigned)f2bf(hp1) << 16);
      unsigned p32b = (unsigned)__shfl((int)p32, (l + 2) & 63);
      if ((l & 3) == 0) {
        unsigned long long p64 =
            (unsigned long long)p32 | ((unsigned long long)p32b << 32);
        unsigned long long* dst =
            (unsigned long long*)((char*)hx + (size_t)(cur ^ 1) * 65536) +
            b * 128 + (j >> 2);
        __hip_atomic_store(dst, p64, __ATOMIC_RELAXED, __HIP_MEMORY_SCOPE_AGENT);
      }
      outbf[((size_t)b * 512 + t) * 512 + j] = m ? hb : (unsigned short)0;
    }
    // ---- MFMA dir1 (overlaps hA store drain window) ----
    f32x4 aB0 = f32x4{0.f, 0.f, 0.f, 0.f}, aB1 = f32x4{0.f, 0.f, 0.f, 0.f};
#pragma unroll
    for (int kc = 0; kc < 8; ++kc) {
      bf16x8 av = __builtin_bit_cast(bf16x8, fB[kc]);
      int kg = (kh * 8 + kc) * 4 + q;
      bf16x8 b0v = *(const bf16x8*)(smem + 32768 + r0 * 1024 + (kg ^ (r0 & 7)) * 16);
      bf16x8 b1v = *(const bf16x8*)(smem + 32768 + r1 * 1024 + (kg ^ (r1 & 7)) * 16);
      aB0 = MFMA16(av, b0v, aB0);
      aB1 = MFMA16(av, b1v, aB1);
    }
    {
      float* gB = gex + 4352 + kh * 2176;
#pragma unroll
      for (int i = 0; i < 4; ++i) {
        gB[(16 * mh + 4 * q + i) * 34 + r0] = aB0[i];
        gB[(16 * mh + 4 * q + i) * 34 + r1] = aB1[i];
      }
    }
    __syncthreads();  // S2: hA stores drained wg-wide + gexB ready
    if (tid == 0 && tl + 1 < Tc)
      __hip_atomic_store(&arrv[wg], (unsigned)(tl + 1), __ATOMIC_RELAXED,
                         __HIP_MEMORY_SCOPE_AGENT);
    // ---- gate dir1 + hB store ----
    {
      const float* gx = gex + 4352;
      float g0 = gx[b * 34 + jj]      + gx[2176 + b * 34 + jj]      + xB0;
      float g1 = gx[b * 34 + 8 + jj]  + gx[2176 + b * 34 + 8 + jj]  + xB1;
      float g2 = gx[b * 34 + 16 + jj] + gx[2176 + b * 34 + 16 + jj] + xB2;
      float g3 = gx[b * 34 + 24 + jj] + gx[2176 + b * 34 + 24 + jj] + xB3;
      float ig = 1.f / (1.f + expf(-g0));
      float fg = 1.f / (1.f + expf(-g1));
      float gg = tanhf(g2);
      float og = 1.f / (1.f + expf(-g3));
      float cn = fg * c1 + ig * gg;
      float hn = og * tanhf(cn);
      c1 = m ? cn : c1;
      h1 = m ? hn : h1;
      unsigned short hb = f2bf(h1);
      float hp1 = __shfl(h1, (l + 1) & 63);
      unsigned p32 = (unsigned)hb | ((unsigned)f2bf(hp1) << 16);
      unsigned p32b = (unsigned)__shfl((int)p32, (l + 2) & 63);
      if ((l & 3) == 0) {
        unsigned long long p64 =
            (unsigned long long)p32 | ((unsigned long long)p32b << 32);
        unsigned long long* dst =
            (unsigned long long*)((char*)hx + (size_t)(2 + (cur ^ 1)) * 65536) +
            b * 128 + (j >> 2);
        __hip_atomic_store(dst, p64, __ATOMIC_RELAXED, __HIP_MEMORY_SCOPE_AGENT);
      }
      if (m) {
        int tp = lenb - 1 - t;
        outbf[(size_t)16777216 + ((size_t)b * 512 + tp) * 512 + j] = hb;
      }
    }
    __syncthreads();  // S3: hB stores drained
    if (tid == 0 && tl + 1 < Tc)
      __hip_atomic_store(&arrv[64 + wg], (unsigned)(tl + 1), __ATOMIC_RELAXED,
                         __HIP_MEMORY_SCOPE_AGENT);
    // rotate xp prefetch
    xA0 = nA0; xA1 = nA1; xA2 = nA2; xA3 = nA3;
    xB0 = nB0; xB1 = nB1; xB2 = nB2; xB3 = nB3;
  }
  Cst[s0] = c0; Hst[s0] = h0;
  Cst[s1] = c1; Hst[s1] = h1;
}

// ---------------- emissions (unchanged) ----------------
__global__ __launch_bounds__(256) void emis_kernel(
    const unsigned short* __restrict__ outbf, const float* __restrict__ Wout,
    const float* __restrict__ bout, float* __restrict__ emis) {
  __shared__ float red[64][25][4];
  int tid = threadIdx.x;
  int p = tid >> 6, rr = tid & 63;
  int r = blockIdx.x * 64 + rr;
  int b = r >> 9, t = r & 511;
  int dir = p >> 1;
  int jq = (p & 1) * 256;
  const unsigned short* hp =
      outbf + (size_t)dir * 16777216 + ((size_t)b * 512 + t) * 512 + jq;
  float acc[24];
#pragma unroll
  for (int i = 0; i < 24; ++i) acc[i] = 0.f;
  for (int kc = 0; kc < 32; ++kc) {
    uint4 vh = *(const uint4*)(hp + kc * 8);
    unsigned uh[4] = {vh.x, vh.y, vh.z, vh.w};
    float f[8];
#pragma unroll
    for (int z = 0; z < 4; ++z) {
      f[2 * z] = bf2f((unsigned short)(uh[z] & 0xffff));
      f[2 * z + 1] = bf2f((unsigned short)(uh[z] >> 16));
    }
    const float* wbase = Wout + dir * 512 + jq + kc * 8;
#pragma unroll
    for (int nn = 0; nn < 24; ++nn) {
      const float* wr = wbase + nn * 1024;
      float4 w0 = *(const float4*)(wr);
      float4 w1 = *(const float4*)(wr + 4);
      acc[nn] += f[0] * w0.x + f[1] * w0.y + f[2] * w0.z + f[3] * w0.w +
                 f[4] * w1.x + f[5] * w1.y + f[6] * w1.z + f[7] * w1.w;
    }
  }
#pragma unroll
  for (int nn = 0; nn < 24; ++nn) red[rr][nn][p] = acc[nn];
  __syncthreads();
#pragma unroll
  for (int oi = 0; oi < 6; ++oi) {
    int idx = tid + 256 * oi;
    int rr2 = idx / 24, n2 = idx % 24;
    float v = red[rr2][n2][0] + red[rr2][n2][1] + red[rr2][n2][2] +
              red[rr2][n2][3] + bout[n2];
    emis[((size_t)blockIdx.x * 64 + rr2) * 24 + n2] = v;
  }
}

// ---------------- Viterbi (unchanged) ----------------
__global__ __launch_bounds__(64) void viterbi_kernel(
    const float* __restrict__ emis, const int* __restrict__ length,
    const float* __restrict__ trans, float* __restrict__ out) {
  __shared__ float eb[12288];
  __shared__ float tr[576];
  __shared__ unsigned char bp[512 * 24];
  __shared__ unsigned char seq[512];
  int b = blockIdx.x, l = threadIdx.x;
  const float* ebg = emis + (size_t)b * 12288;
  for (int i = l * 4; i < 12288; i += 256)
    *(float4*)(eb + i) = *(const float4*)(ebg + i);
  for (int i = l; i < 576; i += 64) tr[i] = trans[i];
  __syncthreads();
  int lc = (l < 24) ? l : 0;
  float tcol[24];
#pragma unroll
  for (int p = 0; p < 24; ++p) tcol[p] = tr[p * 24 + lc];
  int len = length[b];
  float alpha = (l < 24) ? eb[lc] + tr[22 * 24 + lc] : -3e38f;
  for (int t = 1; t < 512; ++t) {
    float mx = -3e38f;
    int arg = 0;
#pragma unroll
    for (int p = 0; p < 24; ++p) {
      float v = __shfl(alpha, p) + tcol[p];
      if (v > mx) { mx = v; arg = p; }
    }
    if (l < 24) {
      bp[t * 24 + l] = (unsigned char)arg;
      if (t < len) alpha = mx + eb[t * 24 + l];
    }
  }
  float fin = (l < 24) ? alpha + tr[lc * 24 + 23] : -3e38f;
  float best = -3e38f;
  int cur = 0;
  for (int p = 0; p < 24; ++p) {
    float v = __shfl(fin, p);
    if (v > best) { best = v; cur = p; }
  }
  int last = len - 1;
  if (l == 0) {
    out[b] = best;
    int c = cur;
    for (int t = 511; t >= 0; --t) {
      seq[t] = (unsigned char)c;
      if (t >= 1 && t <= last) c = bp[t * 24 + c];
    }
  }
  __syncthreads();
  for (int i = l; i < 512; i += 64) out[64 + b * 512 + i] = (float)seq[i];
}

// ---------------- host ----------------
extern "C" void kernel_launch(void* const* d_in, const int* in_sizes, int n_in,
                              void* d_out, int out_size, void* d_ws, size_t ws_size,
                              hipStream_t stream) {
  const float* X = (const float*)d_in[0];
  const int* length = (const int*)d_in[2];
  const float* Wih_f = (const float*)d_in[3];
  const float* Whh_f = (const float*)d_in[4];
  const float* b_f = (const float*)d_in[5];
  const float* Wih_b = (const float*)d_in[6];
  const float* Whh_b = (const float*)d_in[7];
  const float* b_b = (const float*)d_in[8];
  const float* Wout = (const float*)d_in[9];
  const float* bout = (const float*)d_in[10];
  const float* trans = (const float*)d_in[11];

  char* ws = (char*)d_ws;
  unsigned short* whh_bf = (unsigned short*)(ws + O_WHHB);
  unsigned short* wih_bf = (unsigned short*)(ws + O_WIHB);
  unsigned short* xb = (unsigned short*)(ws + O_XB);
  unsigned short* outbf = (unsigned short*)(ws + O_OUT);
  unsigned* hx = (unsigned*)(ws + O_HX);
  float* Hbuf = (float*)(ws + O_HF);
  float* Cbuf = (float*)(ws + O_CF);
  float* emis = (float*)(ws + O_EMIS);
  unsigned* bar = (unsigned*)(ws + O_BAR);
  float* xp = (float*)(ws + O_XP);

  int Tc = 2;
  const int cands[9] = {512, 256, 128, 64, 32, 16, 8, 4, 2};
  for (int i = 0; i < 9; ++i) {
    if (O_XP + (size_t)cands[i] * 1048576 <= ws_size) { Tc = cands[i]; break; }
  }
  int nch = T_ / Tc;

  hipMemsetAsync(ws + O_OUT, 0, SZ_OUT, stream);
  hipMemsetAsync(ws + O_HX, 0, SZ_HX, stream);

  cast_bf<<<1024, 256, 0, stream>>>(Whh_f, whh_bf, 1048576);
  cast_bf<<<1024, 256, 0, stream>>>(Whh_b, whh_bf + 1048576, 1048576);
  cast_bf<<<1024, 256, 0, stream>>>(Wih_f, wih_bf, 1048576);
  cast_bf<<<1024, 256, 0, stream>>>(Wih_b, wih_bf + 1048576, 1048576);
  cast_bf<<<4096, 256, 0, stream>>>(X, xb, 16777216);

  for (int ch = 0; ch < nch; ++ch) {
    int t0 = ch * Tc;
    xp_gemm<<<dim3(Tc * 64 / 128, 16, 2), 256, 0, stream>>>(
        xb, wih_bf, b_f, b_b, length, xp, t0, Tc);
    hipMemsetAsync(bar, 0, 512, stream);
    lstm_persist<<<64, 512, 0, stream>>>(whh_bf, hx, xp, length, Cbuf, Hbuf,
                                         outbf, bar, t0, Tc);
  }
  emis_kernel<<<512, 256, 0, stream>>>(outbf, Wout, bout, emis);
  viterbi_kernel<<<64, 64, 0, stream>>>(emis, length, trans, (float*)d_out);
}